// Round 17
// baseline (549.671 us; speedup 1.0000x reference)
//
#include <hip/hip_runtime.h>

#define NROWS 32
#define NPB   262144
#define LOG2_NPB 18
#define K_SEL 13107u
#define NTOT  (NROWS * NPB)
#define VF 8

// k_std geometry: 2 rows per block, 16 chain lanes (8 VF-lanes x 2 rows)
#define NROWB  2
#define NBLK   (NROWS / NROWB)   // 16 chain blocks
#define TILE_R 4096              // floats per row per tile
#define NTILE  (NPB / TILE_R)    // 64 tiles
#define TRC    (TILE_R / VF)     // 512 floats per lane-row per tile
#define TRCP   (TRC + 4)         // padded: lane stride 516 -> bank base 4*lane
#define GBLK   240               // g-precompute blocks
#define SLOADS 11                // ceil(2048/192) float4 loads per stager

typedef __attribute__((ext_vector_type(4))) float f32x4;

// ---------- ws layout (byte offsets) ----------
#define OFF_BETA  4224     // float[32]
#define OFF_CNT   4352     // uint[4][32][256] = 131072 (zeroed)
#define OFF_ACTS  1048576                    // float[NTOT] acts-key cache
#define OFF_G     (OFF_ACTS + (size_t)NTOT*4) // float[NTOT] g cache
#define WS_NEED_ACTS (OFF_ACTS + (size_t)NTOT * 4)
#define WS_NEED_G    (OFF_G    + (size_t)NTOT * 4)

// ======== XLA:CPU f32 log twin (GenerateVF32Log / Eigen plog, Cephes) ========
// Unfused mul+add at every MulAdd. FROZEN: bits validated round 8.
__device__ __forceinline__ float xla_logf(float xf) {
    unsigned b = __float_as_uint(xf);
    float e = (float)(int)((b >> 23) - 126u);
    float m = __uint_as_float((b & 0x007FFFFFu) | 0x3F000000u);   // [0.5,1)
    bool mk = m < 0.707106781186547524f;
    float tmp = mk ? m : 0.0f;
    if (mk) e = __fsub_rn(e, 1.0f);
    float x = __fadd_rn(__fsub_rn(m, 1.0f), tmp);
    float z  = __fmul_rn(x, x);
    float x3 = __fmul_rn(z, x);
    float y  = __fadd_rn(__fmul_rn( 7.0376836292e-2f, x), -1.1514610310e-1f);
    float y1 = __fadd_rn(__fmul_rn(-1.2420140846e-1f, x),  1.4249322787e-1f);
    float y2 = __fadd_rn(__fmul_rn( 2.0000714765e-1f, x), -2.4999993993e-1f);
    y  = __fadd_rn(__fmul_rn(y,  x),  1.1676998740e-1f);
    y1 = __fadd_rn(__fmul_rn(y1, x), -1.6668057665e-1f);
    y2 = __fadd_rn(__fmul_rn(y2, x),  3.3333331174e-1f);
    y  = __fadd_rn(__fmul_rn(y, x3), y1);
    y  = __fadd_rn(__fmul_rn(y, x3), y2);
    y  = __fmul_rn(y, x3);
    y  = __fadd_rn(__fmul_rn(e, -2.12194440e-4f), y);
    y  = __fsub_rn(y, __fmul_rn(z, 0.5f));
    x  = __fadd_rn(x, y);
    x  = __fadd_rn(__fmul_rn(e, 0.693359375f), x);
    return x;
}

__device__ __forceinline__ float g_of(float uf) {
    float i1 = xla_logf(uf);
    float i3 = xla_logf(-i1);
    return -i3;
}

__device__ __forceinline__ unsigned key_from_g(float xf, float gf, float bt) {
    float a = fmaxf(__fadd_rn(xf, __fmul_rn(bt, gf)), 0.0f);
    unsigned key = __float_as_uint(a);
    if (key == 0x80000000u) key = 0u;
    return key;
}

__device__ __forceinline__ unsigned act_key(float xf, float uf, float bt) {
    return key_from_g(xf, g_of(uf), bt);
}

// ---- inline-asm chain plumbing ----
__device__ __forceinline__ unsigned lds_addr(const void* p) {
    return (unsigned)(size_t)p;    // LDS aperture: truncation = LDS offset
}

#define ISSUE8(r0,r1,r2,r3,r4,r5,r6,r7, ADDR)                                \
    asm volatile("ds_read_b128 %0, %8 offset:0\n\t"                          \
                 "ds_read_b128 %1, %8 offset:16\n\t"                         \
                 "ds_read_b128 %2, %8 offset:32\n\t"                         \
                 "ds_read_b128 %3, %8 offset:48\n\t"                         \
                 "ds_read_b128 %4, %8 offset:64\n\t"                         \
                 "ds_read_b128 %5, %8 offset:80\n\t"                         \
                 "ds_read_b128 %6, %8 offset:96\n\t"                         \
                 "ds_read_b128 %7, %8 offset:112"                            \
                 : "=&v"(r0), "=&v"(r1), "=&v"(r2), "=&v"(r3),               \
                   "=&v"(r4), "=&v"(r5), "=&v"(r6), "=&v"(r7)                \
                 : "v"(ADDR) : "memory")

#define WAIT8  do { asm volatile("s_waitcnt lgkmcnt(8)" ::: "memory");       \
                    __builtin_amdgcn_sched_barrier(0); } while (0)
#define WAIT0  do { asm volatile("s_waitcnt lgkmcnt(0)" ::: "memory");       \
                    __builtin_amdgcn_sched_barrier(0); } while (0)

#define ADD4(r)  do { p = __fadd_rn(p, r.x); p = __fadd_rn(p, r.y);          \
                      p = __fadd_rn(p, r.z); p = __fadd_rn(p, r.w); } while (0)
#define ADD32(r0,r1,r2,r3,r4,r5,r6,r7)                                       \
    do { ADD4(r0); ADD4(r1); ADD4(r2); ADD4(r3);                             \
         ADD4(r4); ADD4(r5); ADD4(r6); ADD4(r7); } while (0)

#define ISSUE_A ISSUE8(A0,A1,A2,A3,A4,A5,A6,A7
#define ISSUE_B ISSUE8(B0,B1,B2,B3,B4,B5,B6,B7
#define ADD_A   ADD32(A0,A1,A2,A3,A4,A5,A6,A7)
#define ADD_B   ADD32(B0,B1,B2,B3,B4,B5,B6,B7)

// stager: 2 rows x 4096 floats per tile; issue ALL global loads first,
// then transposed LDS writes (T14 split, proven R16).
__device__ __forceinline__ void stage_tile2(const float* __restrict__ xr0,
                                            const float* __restrict__ xr1,
                                            float (*dst)[VF][TRCP],
                                            int st, int mode, float m0, float m1) {
    float4 r[SLOADS];
    #pragma unroll
    for (int j = 0; j < SLOADS; j++) {
        int idx = st + j * 192;            // float4 index in [0, 2048)
        if (idx < 2048) {
            int row = idx >> 10;           // 1024 float4 per row
            int f4  = idx & 1023;
            const float* src = row ? xr1 : xr0;
            r[j] = ((const float4*)src)[f4];
        }
    }
    asm volatile("" ::: "memory");   // loads issued above; writes stay below
    #pragma unroll
    for (int j = 0; j < SLOADS; j++) {
        int idx = st + j * 192;
        if (idx < 2048) {
            int row = idx >> 10;
            int f4  = idx & 1023;
            float mean = row ? m1 : m0;
            #pragma unroll
            for (int q = 0; q < 4; q++) {
                int g = f4 * 4 + q;        // element index within row-tile
                float v = (&r[j].x)[q];
                if (mode) { float c = __fsub_rn(v, mean); v = __fmul_rn(c, c); }
                dst[row][g & 7][g >> 3] = v;
            }
        }
    }
}

// ======== k_std: XLA VF=8 reduce twin, 2 rows/block + fused g-precompute ====
// Blocks 0..15: rows 2b, 2b+1. Wave 0 lanes 0-15 (= 2 rows x 8 VF-lanes) run
// the exact sequential __fadd_rn chains; each ds_read_b128 now serves 16
// lanes (256B vs R16's 128B) halving per-row DS service load (the R16
// bottleneck: DS pipe service ~= VALU time, summed not overlapped).
// Threads 64-255 stage+transpose; blocks 16+: g-precompute.
__global__ __launch_bounds__(256, 1) void k_std(const float* __restrict__ x,
                                                const float* __restrict__ u,
                                                float* __restrict__ beta_out,
                                                float* __restrict__ g_out) {
    __shared__ __align__(16) float buf[2][NROWB][VF][TRCP];  // 66048 B
    __shared__ float partial[NROWB][VF];
    __shared__ float mean_sh[NROWB];
    int tid = threadIdx.x;

    if (blockIdx.x >= NBLK) {                  // ---- g-precompute blocks ----
        if (!g_out) return;
        const float4* u4 = (const float4*)u;
        float4* g4 = (float4*)g_out;
        int idx = (blockIdx.x - NBLK) * 256 + tid;
        int stride = GBLK * 256;
        for (int i = idx; i < NTOT / 4; i += stride) {
            float4 uu = u4[i];
            float4 gg;
            gg.x = g_of(uu.x); gg.y = g_of(uu.y);
            gg.z = g_of(uu.z); gg.w = g_of(uu.w);
            g4[i] = gg;
        }
        return;
    }

    const float* xr0 = x + (size_t)(NROWB * blockIdx.x) * NPB;
    const float* xr1 = xr0 + NPB;

    for (int mode = 0; mode < 2; mode++) {
        float m0 = (mode == 1) ? mean_sh[0] : 0.0f;
        float m1 = (mode == 1) ? mean_sh[1] : 0.0f;
        if (tid >= 64)
            stage_tile2(xr0, xr1, buf[0], tid - 64, mode, m0, m1);
        __syncthreads();

        float p = 0.0f;
        for (int t = 0; t < NTILE; t++) {
            if (tid < NROWB * VF) {
                // depth-2 pipeline over 16 chunks of 32 floats (lane = tid:
                // row tid>>3, vf tid&7; LDS lane stride 516 -> bank 4*tid,
                // lanes tid / tid+8 alias 2-way = free)
                unsigned base = lds_addr(&buf[t & 1][tid >> 3][tid & 7][0]);
                f32x4 A0, A1, A2, A3, A4, A5, A6, A7;
                f32x4 B0, B1, B2, B3, B4, B5, B6, B7;
                ISSUE_A, base);            // chunk 0
                unsigned ad = base;
                #pragma unroll 1
                for (int c = 0; c < 14; c += 2) {
                    ISSUE_B, ad + 128);    // chunk c+1
                    WAIT8; ADD_A;          // chunk c
                    ISSUE_A, ad + 256);    // chunk c+2
                    WAIT8; ADD_B;          // chunk c+1
                    ad += 256;
                }
                ISSUE_B, ad + 128);        // chunk 15
                WAIT8; ADD_A;              // chunk 14
                WAIT0; ADD_B;              // chunk 15
            } else if (tid >= 64 && t + 1 < NTILE) {
                stage_tile2(xr0 + (size_t)(t + 1) * TILE_R,
                            xr1 + (size_t)(t + 1) * TILE_R,
                            buf[(t + 1) & 1], tid - 64, mode, m0, m1);
            }
            __syncthreads();
        }
        if (tid < NROWB * VF) partial[tid >> 3][tid & 7] = p;
        __syncthreads();
        if (tid < NROWB) {
            float tr[VF];
            for (int j = 0; j < VF; j++) tr[j] = partial[tid][j];
            for (int w = VF / 2; w >= 1; w >>= 1)
                for (int j = 0; j < w; j++) tr[j] = __fadd_rn(tr[j], tr[j + w]);
            float S = tr[0];
            if (mode == 0) {
                mean_sh[tid] = __fdiv_rn(S, 262144.0f);
            } else {
                float var = __fdiv_rn(S, 262143.0f);
                float sd  = __fsqrt_rn(var);
                beta_out[NROWB * blockIdx.x + tid] = __fdiv_rn(sd, (float)(0.1 + 1e-6));
            }
        }
        __syncthreads();
    }
}

// ================= exact MSB radix-select (4 x 8-bit digits) =================
__device__ const unsigned pass_himask[4] = {0x00000000u, 0xFF000000u, 0xFFFF0000u, 0xFFFFFF00u};
__device__ const int      pass_shift[4]  = {24, 16, 8, 0};

// recompute (prefix,rank-chain) from cnt arrays for passes [0, upto)
__device__ unsigned scan_sel(const unsigned* __restrict__ cnt_all, int row, int upto) {
    unsigned pfx = 0, r = K_SEL;
    for (int pp = 0; pp < upto; pp++) {
        const unsigned* h = cnt_all + ((size_t)pp * NROWS + row) * 256;
        int sh = pass_shift[pp];
        unsigned c = 0;
        for (int v = 255; v >= 0; v--) {
            unsigned hv = h[v];
            if (c + hv >= r) { pfx |= (unsigned)v << sh; r -= c; break; }
            c += hv;
        }
    }
    return pfx;
}

// pass 0: vectorized key build (x4 + g4), acts cache write, zero-skip hist
__global__ void k_hist0(const float* __restrict__ x, const float* __restrict__ u,
                        const float* __restrict__ g, const float* __restrict__ beta,
                        float* __restrict__ acts_out, unsigned* __restrict__ cnt) {
    __shared__ unsigned lh[256];
    int row = blockIdx.x >> 4, blk = blockIdx.x & 15;
    lh[threadIdx.x] = 0;
    __syncthreads();
    float bt = beta[row];
    size_t base4 = ((size_t)row * NPB + (size_t)blk * (NPB / 16)) / 4;
    const float4* x4 = (const float4*)x;
    const float4* g4 = (const float4*)g;
    float4* a4 = (float4*)acts_out;
    unsigned zc = 0;
    for (int i = threadIdx.x; i < NPB / 16 / 4; i += 256) {
        float4 xx = x4[base4 + i];
        unsigned k[4];
        if (g) {
            float4 gg = g4[base4 + i];
            k[0] = key_from_g(xx.x, gg.x, bt); k[1] = key_from_g(xx.y, gg.y, bt);
            k[2] = key_from_g(xx.z, gg.z, bt); k[3] = key_from_g(xx.w, gg.w, bt);
        } else {
            const float4 uu = ((const float4*)u)[base4 + i];
            k[0] = act_key(xx.x, uu.x, bt); k[1] = act_key(xx.y, uu.y, bt);
            k[2] = act_key(xx.z, uu.z, bt); k[3] = act_key(xx.w, uu.w, bt);
        }
        if (acts_out) {
            float4 av;
            av.x = __uint_as_float(k[0]); av.y = __uint_as_float(k[1]);
            av.z = __uint_as_float(k[2]); av.w = __uint_as_float(k[3]);
            a4[base4 + i] = av;
        }
        #pragma unroll
        for (int q = 0; q < 4; q++) {
            if (k[q]) atomicAdd(&lh[k[q] >> 24], 1u);
            else      zc++;
        }
    }
    if (zc) atomicAdd(&lh[0], zc);
    __syncthreads();
    if (lh[threadIdx.x])
        atomicAdd(&cnt[(size_t)row * 256 + threadIdx.x], lh[threadIdx.x]);
}

// passes 1-3: inline prefix recompute (k_sel folded in), vectorized acts read
__global__ void k_histN(const float* __restrict__ x, const float* __restrict__ u,
                        const float* __restrict__ beta, const float* __restrict__ acts_in,
                        const unsigned* __restrict__ cnt_all, unsigned* __restrict__ cnt_out,
                        int p) {
    __shared__ unsigned lh[256];
    __shared__ unsigned pfx_sh;
    int row = blockIdx.x >> 4, blk = blockIdx.x & 15;
    lh[threadIdx.x] = 0;
    if (threadIdx.x == 0) pfx_sh = scan_sel(cnt_all, row, p);
    __syncthreads();
    unsigned pfx = pfx_sh;
    unsigned hm  = pass_himask[p];
    int sh = pass_shift[p];
    size_t base = (size_t)row * NPB + (size_t)blk * (NPB / 16);
    if (acts_in) {
        const float4* a4 = (const float4*)(acts_in + base);
        for (int i = threadIdx.x; i < NPB / 16 / 4; i += 256) {
            float4 av = a4[i];
            #pragma unroll
            for (int q = 0; q < 4; q++) {
                unsigned key = __float_as_uint((&av.x)[q]);
                if ((key & hm) == pfx)
                    atomicAdd(&lh[(key >> sh) & 255u], 1u);
            }
        }
    } else {
        float bt = beta[row];
        for (int i = threadIdx.x; i < NPB / 16; i += 256) {
            unsigned key = act_key(x[base + i], u[base + i], bt);
            if ((key & hm) == pfx)
                atomicAdd(&lh[(key >> sh) & 255u], 1u);
        }
    }
    __syncthreads();
    if (lh[threadIdx.x])
        atomicAdd(&cnt_out[(size_t)row * 256 + threadIdx.x], lh[threadIdx.x]);
}

__global__ void k_write(const float* __restrict__ x, const float* __restrict__ u,
                        const float* __restrict__ beta, const float* __restrict__ acts_in,
                        const unsigned* __restrict__ cnt_all, float* __restrict__ out) {
    __shared__ unsigned kb_sh;
    size_t e4 = (size_t)blockIdx.x * 256 + threadIdx.x;     // float4 index
    int row = (int)(e4 >> (LOG2_NPB - 2));
    if (threadIdx.x == 0) kb_sh = scan_sel(cnt_all, row, 4);
    __syncthreads();
    unsigned kb = kb_sh;
    unsigned k[4];
    if (acts_in) {
        float4 av = ((const float4*)acts_in)[e4];
        #pragma unroll
        for (int q = 0; q < 4; q++) k[q] = __float_as_uint((&av.x)[q]);
    } else {
        float bt = beta[row];
        const float4 xx = ((const float4*)x)[e4];
        const float4 uu = ((const float4*)u)[e4];
        k[0] = act_key(xx.x, uu.x, bt); k[1] = act_key(xx.y, uu.y, bt);
        k[2] = act_key(xx.z, uu.z, bt); k[3] = act_key(xx.w, uu.w, bt);
    }
    float4 sp, mk;
    #pragma unroll
    for (int q = 0; q < 4; q++) {
        bool m = (k[q] >= kb);
        (&sp.x)[q] = m ? __uint_as_float(k[q]) : 0.0f;
        (&mk.x)[q] = m ? 1.0f : 0.0f;
    }
    ((float4*)out)[e4] = sp;
    ((float4*)(out + NTOT))[e4] = mk;
}

extern "C" void kernel_launch(void* const* d_in, const int* in_sizes, int n_in,
                              void* d_out, int out_size, void* d_ws, size_t ws_size,
                              hipStream_t stream) {
    const float* x = (const float*)d_in[0];
    const float* u = (const float*)d_in[1];
    float* out = (float*)d_out;
    char* ws = (char*)d_ws;

    float*    beta    = (float*)(ws + OFF_BETA);
    unsigned* cnt     = (unsigned*)(ws + OFF_CNT);
    float*    acts    = (ws_size >= WS_NEED_ACTS) ? (float*)(ws + OFF_ACTS) : nullptr;
    float*    g       = (ws_size >= WS_NEED_G)    ? (float*)(ws + OFF_G)    : nullptr;

    hipMemsetAsync(ws + OFF_CNT, 0, 131072, stream);  // cnt (all 4 passes)

    k_std<<<NBLK + GBLK, 256, 0, stream>>>(x, u, beta, g);

    k_hist0<<<NROWS * 16, 256, 0, stream>>>(x, u, g, beta, acts, cnt);
    for (int p = 1; p < 4; p++)
        k_histN<<<NROWS * 16, 256, 0, stream>>>(x, u, beta, acts, cnt,
                                                cnt + (size_t)p * NROWS * 256, p);

    k_write<<<NTOT / 4 / 256, 256, 0, stream>>>(x, u, beta, acts, cnt, out);
}

// Round 18
// 326.122 us; speedup vs baseline: 1.6855x; 1.6855x over previous
//
#include <hip/hip_runtime.h>

#define NROWS 32
#define NPB   262144
#define LOG2_NPB 18
#define K_SEL 13107u
#define NTOT  (NROWS * NPB)
#define VF 8

// k_std geometry: 2 rows per block, 16 chain lanes (8 VF-lanes x 2 rows)
#define NROWB  2
#define NBLK   (NROWS / NROWB)   // 16 chain blocks
#define TILE_R 4096              // floats per row per tile
#define NTILE  (NPB / TILE_R)    // 64 tiles
#define TRC    (TILE_R / VF)     // 512 floats per lane-row per tile
#define TRCP   (TRC + 4)         // padded: lane stride 516 -> bank base 4*lane
#define GBLK   240               // g-precompute blocks
#define SLOADS 11                // ceil(2048/192) float4 loads per stager

typedef __attribute__((ext_vector_type(4))) float f32x4;

// ---------- ws layout (byte offsets) ----------
#define OFF_BETA  4224     // float[32]
#define OFF_CNT   4352     // uint[4][32][256] = 131072 (zeroed)
#define OFF_PFX   135424   // uint[32] (zeroed)
#define OFF_RANK  135552   // uint[32] (zeroed)
#define OFF_ACTS  1048576                    // float[NTOT] acts-key cache
#define OFF_G     (OFF_ACTS + (size_t)NTOT*4) // float[NTOT] g cache
#define WS_NEED_ACTS (OFF_ACTS + (size_t)NTOT * 4)
#define WS_NEED_G    (OFF_G    + (size_t)NTOT * 4)

// ======== XLA:CPU f32 log twin (GenerateVF32Log / Eigen plog, Cephes) ========
// Unfused mul+add at every MulAdd. FROZEN: bits validated round 8.
__device__ __forceinline__ float xla_logf(float xf) {
    unsigned b = __float_as_uint(xf);
    float e = (float)(int)((b >> 23) - 126u);
    float m = __uint_as_float((b & 0x007FFFFFu) | 0x3F000000u);   // [0.5,1)
    bool mk = m < 0.707106781186547524f;
    float tmp = mk ? m : 0.0f;
    if (mk) e = __fsub_rn(e, 1.0f);
    float x = __fadd_rn(__fsub_rn(m, 1.0f), tmp);
    float z  = __fmul_rn(x, x);
    float x3 = __fmul_rn(z, x);
    float y  = __fadd_rn(__fmul_rn( 7.0376836292e-2f, x), -1.1514610310e-1f);
    float y1 = __fadd_rn(__fmul_rn(-1.2420140846e-1f, x),  1.4249322787e-1f);
    float y2 = __fadd_rn(__fmul_rn( 2.0000714765e-1f, x), -2.4999993993e-1f);
    y  = __fadd_rn(__fmul_rn(y,  x),  1.1676998740e-1f);
    y1 = __fadd_rn(__fmul_rn(y1, x), -1.6668057665e-1f);
    y2 = __fadd_rn(__fmul_rn(y2, x),  3.3333331174e-1f);
    y  = __fadd_rn(__fmul_rn(y, x3), y1);
    y  = __fadd_rn(__fmul_rn(y, x3), y2);
    y  = __fmul_rn(y, x3);
    y  = __fadd_rn(__fmul_rn(e, -2.12194440e-4f), y);
    y  = __fsub_rn(y, __fmul_rn(z, 0.5f));
    x  = __fadd_rn(x, y);
    x  = __fadd_rn(__fmul_rn(e, 0.693359375f), x);
    return x;
}

__device__ __forceinline__ float g_of(float uf) {
    float i1 = xla_logf(uf);
    float i3 = xla_logf(-i1);
    return -i3;
}

__device__ __forceinline__ unsigned key_from_g(float xf, float gf, float bt) {
    float a = fmaxf(__fadd_rn(xf, __fmul_rn(bt, gf)), 0.0f);
    unsigned key = __float_as_uint(a);
    if (key == 0x80000000u) key = 0u;
    return key;
}

__device__ __forceinline__ unsigned act_key(float xf, float uf, float bt) {
    return key_from_g(xf, g_of(uf), bt);
}

// ---- inline-asm chain plumbing ----
__device__ __forceinline__ unsigned lds_addr(const void* p) {
    return (unsigned)(size_t)p;    // LDS aperture: truncation = LDS offset
}

#define ISSUE8(r0,r1,r2,r3,r4,r5,r6,r7, ADDR)                                \
    asm volatile("ds_read_b128 %0, %8 offset:0\n\t"                          \
                 "ds_read_b128 %1, %8 offset:16\n\t"                         \
                 "ds_read_b128 %2, %8 offset:32\n\t"                         \
                 "ds_read_b128 %3, %8 offset:48\n\t"                         \
                 "ds_read_b128 %4, %8 offset:64\n\t"                         \
                 "ds_read_b128 %5, %8 offset:80\n\t"                         \
                 "ds_read_b128 %6, %8 offset:96\n\t"                         \
                 "ds_read_b128 %7, %8 offset:112"                            \
                 : "=&v"(r0), "=&v"(r1), "=&v"(r2), "=&v"(r3),               \
                   "=&v"(r4), "=&v"(r5), "=&v"(r6), "=&v"(r7)                \
                 : "v"(ADDR) : "memory")

#define WAIT8  do { asm volatile("s_waitcnt lgkmcnt(8)" ::: "memory");       \
                    __builtin_amdgcn_sched_barrier(0); } while (0)
#define WAIT0  do { asm volatile("s_waitcnt lgkmcnt(0)" ::: "memory");       \
                    __builtin_amdgcn_sched_barrier(0); } while (0)

#define ADD4(r)  do { p = __fadd_rn(p, r.x); p = __fadd_rn(p, r.y);          \
                      p = __fadd_rn(p, r.z); p = __fadd_rn(p, r.w); } while (0)
#define ADD32(r0,r1,r2,r3,r4,r5,r6,r7)                                       \
    do { ADD4(r0); ADD4(r1); ADD4(r2); ADD4(r3);                             \
         ADD4(r4); ADD4(r5); ADD4(r6); ADD4(r7); } while (0)

#define ISSUE_A ISSUE8(A0,A1,A2,A3,A4,A5,A6,A7
#define ISSUE_B ISSUE8(B0,B1,B2,B3,B4,B5,B6,B7
#define ADD_A   ADD32(A0,A1,A2,A3,A4,A5,A6,A7)
#define ADD_B   ADD32(B0,B1,B2,B3,B4,B5,B6,B7)

// stager: 2 rows x 4096 floats per tile; issue ALL global loads first,
// then transposed LDS writes (T14 split, proven R16).
__device__ __forceinline__ void stage_tile2(const float* __restrict__ xr0,
                                            const float* __restrict__ xr1,
                                            float (*dst)[VF][TRCP],
                                            int st, int mode, float m0, float m1) {
    float4 r[SLOADS];
    #pragma unroll
    for (int j = 0; j < SLOADS; j++) {
        int idx = st + j * 192;            // float4 index in [0, 2048)
        if (idx < 2048) {
            int row = idx >> 10;           // 1024 float4 per row
            int f4  = idx & 1023;
            const float* src = row ? xr1 : xr0;
            r[j] = ((const float4*)src)[f4];
        }
    }
    asm volatile("" ::: "memory");   // loads issued above; writes stay below
    #pragma unroll
    for (int j = 0; j < SLOADS; j++) {
        int idx = st + j * 192;
        if (idx < 2048) {
            int row = idx >> 10;
            int f4  = idx & 1023;
            float mean = row ? m1 : m0;
            #pragma unroll
            for (int q = 0; q < 4; q++) {
                int g = f4 * 4 + q;        // element index within row-tile
                float v = (&r[j].x)[q];
                if (mode) { float c = __fsub_rn(v, mean); v = __fmul_rn(c, c); }
                dst[row][g & 7][g >> 3] = v;
            }
        }
    }
}

// ======== k_std: XLA VF=8 reduce twin, 2 rows/block + fused g-precompute ====
// Blocks 0..15: rows 2b, 2b+1. Wave 0 lanes 0-15 (= 2 rows x 8 VF-lanes) run
// the exact sequential __fadd_rn chains; each ds_read_b128 serves 16 lanes.
// Threads 64-255 stage+transpose; blocks 16+: g-precompute.
__global__ __launch_bounds__(256, 1) void k_std(const float* __restrict__ x,
                                                const float* __restrict__ u,
                                                float* __restrict__ beta_out,
                                                float* __restrict__ g_out) {
    __shared__ __align__(16) float buf[2][NROWB][VF][TRCP];  // 66048 B
    __shared__ float partial[NROWB][VF];
    __shared__ float mean_sh[NROWB];
    int tid = threadIdx.x;

    if (blockIdx.x >= NBLK) {                  // ---- g-precompute blocks ----
        if (!g_out) return;
        const float4* u4 = (const float4*)u;
        float4* g4 = (float4*)g_out;
        int idx = (blockIdx.x - NBLK) * 256 + tid;
        int stride = GBLK * 256;
        for (int i = idx; i < NTOT / 4; i += stride) {
            float4 uu = u4[i];
            float4 gg;
            gg.x = g_of(uu.x); gg.y = g_of(uu.y);
            gg.z = g_of(uu.z); gg.w = g_of(uu.w);
            g4[i] = gg;
        }
        return;
    }

    const float* xr0 = x + (size_t)(NROWB * blockIdx.x) * NPB;
    const float* xr1 = xr0 + NPB;

    for (int mode = 0; mode < 2; mode++) {
        float m0 = (mode == 1) ? mean_sh[0] : 0.0f;
        float m1 = (mode == 1) ? mean_sh[1] : 0.0f;
        if (tid >= 64)
            stage_tile2(xr0, xr1, buf[0], tid - 64, mode, m0, m1);
        __syncthreads();

        float p = 0.0f;
        for (int t = 0; t < NTILE; t++) {
            if (tid < NROWB * VF) {
                // depth-2 pipeline over 16 chunks of 32 floats (lane = tid:
                // row tid>>3, vf tid&7; LDS lane stride 516 -> bank 4*tid,
                // lanes tid / tid+8 alias 2-way = free)
                unsigned base = lds_addr(&buf[t & 1][tid >> 3][tid & 7][0]);
                f32x4 A0, A1, A2, A3, A4, A5, A6, A7;
                f32x4 B0, B1, B2, B3, B4, B5, B6, B7;
                ISSUE_A, base);            // chunk 0
                unsigned ad = base;
                #pragma unroll 1
                for (int c = 0; c < 14; c += 2) {
                    ISSUE_B, ad + 128);    // chunk c+1
                    WAIT8; ADD_A;          // chunk c
                    ISSUE_A, ad + 256);    // chunk c+2
                    WAIT8; ADD_B;          // chunk c+1
                    ad += 256;
                }
                ISSUE_B, ad + 128);        // chunk 15
                WAIT8; ADD_A;              // chunk 14
                WAIT0; ADD_B;              // chunk 15
            } else if (tid >= 64 && t + 1 < NTILE) {
                stage_tile2(xr0 + (size_t)(t + 1) * TILE_R,
                            xr1 + (size_t)(t + 1) * TILE_R,
                            buf[(t + 1) & 1], tid - 64, mode, m0, m1);
            }
            __syncthreads();
        }
        if (tid < NROWB * VF) partial[tid >> 3][tid & 7] = p;
        __syncthreads();
        if (tid < NROWB) {
            float tr[VF];
            for (int j = 0; j < VF; j++) tr[j] = partial[tid][j];
            for (int w = VF / 2; w >= 1; w >>= 1)
                for (int j = 0; j < w; j++) tr[j] = __fadd_rn(tr[j], tr[j + w]);
            float S = tr[0];
            if (mode == 0) {
                mean_sh[tid] = __fdiv_rn(S, 262144.0f);
            } else {
                float var = __fdiv_rn(S, 262143.0f);
                float sd  = __fsqrt_rn(var);
                beta_out[NROWB * blockIdx.x + tid] = __fdiv_rn(sd, (float)(0.1 + 1e-6));
            }
        }
        __syncthreads();
    }
}

// ================= exact MSB radix-select (4 x 8-bit digits) =================
__device__ const unsigned pass_himask[4] = {0x00000000u, 0xFF000000u, 0xFFFF0000u, 0xFFFFFF00u};
__device__ const int      pass_shift[4]  = {24, 16, 8, 0};

// pass 0: vectorized key build (x4 + g4), acts cache write, zero-skip hist
__global__ void k_hist0(const float* __restrict__ x, const float* __restrict__ u,
                        const float* __restrict__ g, const float* __restrict__ beta,
                        float* __restrict__ acts_out, unsigned* __restrict__ cnt) {
    __shared__ unsigned lh[256];
    int row = blockIdx.x >> 4, blk = blockIdx.x & 15;
    lh[threadIdx.x] = 0;
    __syncthreads();
    float bt = beta[row];
    size_t base4 = ((size_t)row * NPB + (size_t)blk * (NPB / 16)) / 4;
    const float4* x4 = (const float4*)x;
    const float4* g4 = (const float4*)g;
    float4* a4 = (float4*)acts_out;
    unsigned zc = 0;
    for (int i = threadIdx.x; i < NPB / 16 / 4; i += 256) {
        float4 xx = x4[base4 + i];
        unsigned k[4];
        if (g) {
            float4 gg = g4[base4 + i];
            k[0] = key_from_g(xx.x, gg.x, bt); k[1] = key_from_g(xx.y, gg.y, bt);
            k[2] = key_from_g(xx.z, gg.z, bt); k[3] = key_from_g(xx.w, gg.w, bt);
        } else {
            const float4 uu = ((const float4*)u)[base4 + i];
            k[0] = act_key(xx.x, uu.x, bt); k[1] = act_key(xx.y, uu.y, bt);
            k[2] = act_key(xx.z, uu.z, bt); k[3] = act_key(xx.w, uu.w, bt);
        }
        if (acts_out) {
            float4 av;
            av.x = __uint_as_float(k[0]); av.y = __uint_as_float(k[1]);
            av.z = __uint_as_float(k[2]); av.w = __uint_as_float(k[3]);
            a4[base4 + i] = av;
        }
        #pragma unroll
        for (int q = 0; q < 4; q++) {
            if (k[q]) atomicAdd(&lh[k[q] >> 24], 1u);
            else      zc++;
        }
    }
    if (zc) atomicAdd(&lh[0], zc);
    __syncthreads();
    if (lh[threadIdx.x])
        atomicAdd(&cnt[(size_t)row * 256 + threadIdx.x], lh[threadIdx.x]);
}

// passes 1-3: vectorized acts read, conditional (rare) atomics
__global__ void k_histN(const float* __restrict__ x, const float* __restrict__ u,
                        const float* __restrict__ beta, const float* __restrict__ acts_in,
                        unsigned* __restrict__ cnt, const unsigned* __restrict__ prefix, int p) {
    __shared__ unsigned lh[256];
    int row = blockIdx.x >> 4, blk = blockIdx.x & 15;
    lh[threadIdx.x] = 0;
    __syncthreads();
    unsigned pfx = prefix[row];
    unsigned hm  = pass_himask[p];
    int sh = pass_shift[p];
    size_t base = (size_t)row * NPB + (size_t)blk * (NPB / 16);
    if (acts_in) {
        const float4* a4 = (const float4*)(acts_in + base);
        for (int i = threadIdx.x; i < NPB / 16 / 4; i += 256) {
            float4 av = a4[i];
            #pragma unroll
            for (int q = 0; q < 4; q++) {
                unsigned key = __float_as_uint((&av.x)[q]);
                if ((key & hm) == pfx)
                    atomicAdd(&lh[(key >> sh) & 255u], 1u);
            }
        }
    } else {
        float bt = beta[row];
        for (int i = threadIdx.x; i < NPB / 16; i += 256) {
            unsigned key = act_key(x[base + i], u[base + i], bt);
            if ((key & hm) == pfx)
                atomicAdd(&lh[(key >> sh) & 255u], 1u);
        }
    }
    __syncthreads();
    if (lh[threadIdx.x])
        atomicAdd(&cnt[(size_t)row * 256 + threadIdx.x], lh[threadIdx.x]);
}

__global__ void k_sel(const unsigned* __restrict__ cnt, unsigned* prefix, unsigned* rank, int p) {
    if (threadIdx.x != 0) return;
    int row = blockIdx.x;
    unsigned r   = (p == 0) ? K_SEL : rank[row];
    unsigned pfx = (p == 0) ? 0u : prefix[row];
    const unsigned* h = cnt + (size_t)row * 256;
    int sh = pass_shift[p];
    unsigned c = 0;
    for (int v = 255; v >= 0; v--) {
        unsigned hv = h[v];
        if (c + hv >= r) {
            prefix[row] = pfx | ((unsigned)v << sh);
            rank[row]   = r - c;
            return;
        }
        c += hv;
    }
}

__global__ void k_write(const float* __restrict__ x, const float* __restrict__ u,
                        const float* __restrict__ beta, const float* __restrict__ acts_in,
                        const unsigned* __restrict__ prefix, float* __restrict__ out) {
    size_t e4 = (size_t)blockIdx.x * 256 + threadIdx.x;     // float4 index
    int row = (int)(e4 >> (LOG2_NPB - 2));
    unsigned kb = prefix[row];
    unsigned k[4];
    if (acts_in) {
        float4 av = ((const float4*)acts_in)[e4];
        #pragma unroll
        for (int q = 0; q < 4; q++) k[q] = __float_as_uint((&av.x)[q]);
    } else {
        float bt = beta[row];
        const float4 xx = ((const float4*)x)[e4];
        const float4 uu = ((const float4*)u)[e4];
        k[0] = act_key(xx.x, uu.x, bt); k[1] = act_key(xx.y, uu.y, bt);
        k[2] = act_key(xx.z, uu.z, bt); k[3] = act_key(xx.w, uu.w, bt);
    }
    float4 sp, mk;
    #pragma unroll
    for (int q = 0; q < 4; q++) {
        bool m = (k[q] >= kb);
        (&sp.x)[q] = m ? __uint_as_float(k[q]) : 0.0f;
        (&mk.x)[q] = m ? 1.0f : 0.0f;
    }
    ((float4*)out)[e4] = sp;
    ((float4*)(out + NTOT))[e4] = mk;
}

extern "C" void kernel_launch(void* const* d_in, const int* in_sizes, int n_in,
                              void* d_out, int out_size, void* d_ws, size_t ws_size,
                              hipStream_t stream) {
    const float* x = (const float*)d_in[0];
    const float* u = (const float*)d_in[1];
    float* out = (float*)d_out;
    char* ws = (char*)d_ws;

    float*    beta    = (float*)(ws + OFF_BETA);
    unsigned* cnt     = (unsigned*)(ws + OFF_CNT);
    unsigned* prefix  = (unsigned*)(ws + OFF_PFX);
    unsigned* rank    = (unsigned*)(ws + OFF_RANK);
    float*    acts    = (ws_size >= WS_NEED_ACTS) ? (float*)(ws + OFF_ACTS) : nullptr;
    float*    g       = (ws_size >= WS_NEED_G)    ? (float*)(ws + OFF_G)    : nullptr;

    hipMemsetAsync(ws + OFF_CNT, 0, 131328, stream);  // cnt + pfx + rank

    k_std<<<NBLK + GBLK, 256, 0, stream>>>(x, u, beta, g);

    k_hist0<<<NROWS * 16, 256, 0, stream>>>(x, u, g, beta, acts, cnt);
    k_sel  <<<NROWS, 64, 0, stream>>>(cnt, prefix, rank, 0);
    for (int p = 1; p < 4; p++) {
        k_histN<<<NROWS * 16, 256, 0, stream>>>(x, u, beta, acts,
                                                cnt + (size_t)p * NROWS * 256, prefix, p);
        k_sel  <<<NROWS, 64, 0, stream>>>(cnt + (size_t)p * NROWS * 256, prefix, rank, p);
    }

    k_write<<<NTOT / 4 / 256, 256, 0, stream>>>(x, u, beta, acts, prefix, out);
}

// Round 19
// 254.927 us; speedup vs baseline: 2.1562x; 1.2793x over previous
//
#include <hip/hip_runtime.h>

#define NROWS 32
#define NPB   262144
#define LOG2_NPB 18
#define K_SEL 13107u
#define NTOT  (NROWS * NPB)
#define VF 8

// k_std geometry: 2 rows/block, 16 chain lanes, big tiles
#define NROWB  2
#define NBLK   (NROWS / NROWB)   // 16 chain blocks
#define TILE_R 8192              // floats per row per tile
#define NTILE  (NPB / TILE_R)    // 32 tiles
#define TRC    (TILE_R / VF)     // 1024 floats per lane-row per tile
#define TRCP   (TRC + 4)         // padded row: 1028*4 = 4112 B
#define GBLK   240               // g-precompute blocks
#define SLOADS 22                // ceil(4096/192) float4 loads per stager

typedef __attribute__((ext_vector_type(4))) float f32x4;

// ---------- ws layout (byte offsets) ----------
#define OFF_BETA  4224     // float[32]
#define OFF_CNT   4352     // uint[4][32][256] = 131072 (zeroed)
#define OFF_PFX   135424   // uint[32] (zeroed)
#define OFF_RANK  135552   // uint[32] (zeroed)
#define OFF_ACTS  1048576                    // float[NTOT] acts-key cache
#define OFF_G     (OFF_ACTS + (size_t)NTOT*4) // float[NTOT] g cache
#define WS_NEED_ACTS (OFF_ACTS + (size_t)NTOT * 4)
#define WS_NEED_G    (OFF_G    + (size_t)NTOT * 4)

// ======== XLA:CPU f32 log twin (GenerateVF32Log / Eigen plog, Cephes) ========
// Unfused mul+add at every MulAdd. FROZEN: bits validated round 8.
__device__ __forceinline__ float xla_logf(float xf) {
    unsigned b = __float_as_uint(xf);
    float e = (float)(int)((b >> 23) - 126u);
    float m = __uint_as_float((b & 0x007FFFFFu) | 0x3F000000u);   // [0.5,1)
    bool mk = m < 0.707106781186547524f;
    float tmp = mk ? m : 0.0f;
    if (mk) e = __fsub_rn(e, 1.0f);
    float x = __fadd_rn(__fsub_rn(m, 1.0f), tmp);
    float z  = __fmul_rn(x, x);
    float x3 = __fmul_rn(z, x);
    float y  = __fadd_rn(__fmul_rn( 7.0376836292e-2f, x), -1.1514610310e-1f);
    float y1 = __fadd_rn(__fmul_rn(-1.2420140846e-1f, x),  1.4249322787e-1f);
    float y2 = __fadd_rn(__fmul_rn( 2.0000714765e-1f, x), -2.4999993993e-1f);
    y  = __fadd_rn(__fmul_rn(y,  x),  1.1676998740e-1f);
    y1 = __fadd_rn(__fmul_rn(y1, x), -1.6668057665e-1f);
    y2 = __fadd_rn(__fmul_rn(y2, x),  3.3333331174e-1f);
    y  = __fadd_rn(__fmul_rn(y, x3), y1);
    y  = __fadd_rn(__fmul_rn(y, x3), y2);
    y  = __fmul_rn(y, x3);
    y  = __fadd_rn(__fmul_rn(e, -2.12194440e-4f), y);
    y  = __fsub_rn(y, __fmul_rn(z, 0.5f));
    x  = __fadd_rn(x, y);
    x  = __fadd_rn(__fmul_rn(e, 0.693359375f), x);
    return x;
}

__device__ __forceinline__ float g_of(float uf) {
    float i1 = xla_logf(uf);
    float i3 = xla_logf(-i1);
    return -i3;
}

__device__ __forceinline__ unsigned key_from_g(float xf, float gf, float bt) {
    float a = fmaxf(__fadd_rn(xf, __fmul_rn(bt, gf)), 0.0f);
    unsigned key = __float_as_uint(a);
    if (key == 0x80000000u) key = 0u;
    return key;
}

__device__ __forceinline__ unsigned act_key(float xf, float uf, float bt) {
    return key_from_g(xf, g_of(uf), bt);
}

// ---- inline-asm chain plumbing ----
__device__ __forceinline__ unsigned lds_addr(const void* p) {
    return (unsigned)(size_t)p;    // LDS aperture: truncation = LDS offset
}

// 8 ds_read_b128 from one base register with compile-time byte offsets
#define ISSUE8_O(r0,r1,r2,r3,r4,r5,r6,r7, ADDR, OFS)                         \
    asm volatile("ds_read_b128 %0, %8 offset:%c9\n\t"                        \
                 "ds_read_b128 %1, %8 offset:%c10\n\t"                       \
                 "ds_read_b128 %2, %8 offset:%c11\n\t"                       \
                 "ds_read_b128 %3, %8 offset:%c12\n\t"                       \
                 "ds_read_b128 %4, %8 offset:%c13\n\t"                       \
                 "ds_read_b128 %5, %8 offset:%c14\n\t"                       \
                 "ds_read_b128 %6, %8 offset:%c15\n\t"                       \
                 "ds_read_b128 %7, %8 offset:%c16"                           \
                 : "=&v"(r0), "=&v"(r1), "=&v"(r2), "=&v"(r3),               \
                   "=&v"(r4), "=&v"(r5), "=&v"(r6), "=&v"(r7)                \
                 : "v"(ADDR), "i"(OFS), "i"((OFS)+16), "i"((OFS)+32),        \
                   "i"((OFS)+48), "i"((OFS)+64), "i"((OFS)+80),              \
                   "i"((OFS)+96), "i"((OFS)+112)                             \
                 : "memory")

// counted waits; DS is in-order, wait-N certifies all but newest N done.
#define WAIT15 do { asm volatile("s_waitcnt lgkmcnt(15)" ::: "memory");      \
                    __builtin_amdgcn_sched_barrier(0); } while (0)
#define WAIT8  do { asm volatile("s_waitcnt lgkmcnt(8)" ::: "memory");       \
                    __builtin_amdgcn_sched_barrier(0); } while (0)
#define WAIT0  do { asm volatile("s_waitcnt lgkmcnt(0)" ::: "memory");       \
                    __builtin_amdgcn_sched_barrier(0); } while (0)

#define ADD4(r)  do { p = __fadd_rn(p, r.x); p = __fadd_rn(p, r.y);          \
                      p = __fadd_rn(p, r.z); p = __fadd_rn(p, r.w); } while (0)
#define ADD32(r0,r1,r2,r3,r4,r5,r6,r7)                                       \
    do { ADD4(r0); ADD4(r1); ADD4(r2); ADD4(r3);                             \
         ADD4(r4); ADD4(r5); ADD4(r6); ADD4(r7); } while (0)

#define ISSUE_A_O(OFS) ISSUE8_O(A0,A1,A2,A3,A4,A5,A6,A7, base, OFS)
#define ISSUE_B_O(OFS) ISSUE8_O(B0,B1,B2,B3,B4,B5,B6,B7, base, OFS)
#define ISSUE_C_O(OFS) ISSUE8_O(C0,C1,C2,C3,C4,C5,C6,C7, base, OFS)
#define ADD_A   ADD32(A0,A1,A2,A3,A4,A5,A6,A7)
#define ADD_B   ADD32(B0,B1,B2,B3,B4,B5,B6,B7)
#define ADD_C   ADD32(C0,C1,C2,C3,C4,C5,C6,C7)

// batch n -> register set n%3 (A,B,C); adds strictly ascending (XLA order)
#define TRIPLE(K)                                                            \
    ISSUE_C_O(128*(3*K+2)); WAIT15; ADD_A;                                   \
    ISSUE_A_O(128*(3*K+3)); WAIT15; ADD_B;                                   \
    ISSUE_B_O(128*(3*K+4)); WAIT15; ADD_C;

// stager: 2 rows x 8192 floats per tile; issue ALL global loads first,
// then transposed LDS writes (T14 split, proven R16).
__device__ __forceinline__ void stage_tile2(const float* __restrict__ xr0,
                                            const float* __restrict__ xr1,
                                            float (*dst)[VF][TRCP],
                                            int st, int mode, float m0, float m1) {
    float4 r[SLOADS];
    #pragma unroll
    for (int j = 0; j < SLOADS; j++) {
        int idx = st + j * 192;            // float4 index in [0, 4096)
        if (idx < 4096) {
            int row = idx >> 11;           // 2048 float4 per row
            int f4  = idx & 2047;
            const float* src = row ? xr1 : xr0;
            r[j] = ((const float4*)src)[f4];
        }
    }
    asm volatile("" ::: "memory");   // loads issued above; writes stay below
    #pragma unroll
    for (int j = 0; j < SLOADS; j++) {
        int idx = st + j * 192;
        if (idx < 4096) {
            int row = idx >> 11;
            int f4  = idx & 2047;
            float mean = row ? m1 : m0;
            #pragma unroll
            for (int q = 0; q < 4; q++) {
                int g = f4 * 4 + q;        // element index within row-tile
                float v = (&r[j].x)[q];
                if (mode) { float c = __fsub_rn(v, mean); v = __fmul_rn(c, c); }
                dst[row][g & 7][g >> 3] = v;
            }
        }
    }
}

// ======== k_std: XLA VF=8 reduce twin, fully-unrolled immediate chain ======
__global__ __launch_bounds__(256, 1) void k_std(const float* __restrict__ x,
                                                const float* __restrict__ u,
                                                float* __restrict__ beta_out,
                                                float* __restrict__ g_out) {
    __shared__ __align__(16) float buf[2][NROWB][VF][TRCP];  // 131584 B
    __shared__ float partial[NROWB][VF];
    __shared__ float mean_sh[NROWB];
    int tid = threadIdx.x;

    if (blockIdx.x >= NBLK) {                  // ---- g-precompute blocks ----
        if (!g_out) return;
        const float4* u4 = (const float4*)u;
        float4* g4 = (float4*)g_out;
        int idx = (blockIdx.x - NBLK) * 256 + tid;
        int stride = GBLK * 256;
        for (int i = idx; i < NTOT / 4; i += stride) {
            float4 uu = u4[i];
            float4 gg;
            gg.x = g_of(uu.x); gg.y = g_of(uu.y);
            gg.z = g_of(uu.z); gg.w = g_of(uu.w);
            g4[i] = gg;
        }
        return;
    }

    const float* xr0 = x + (size_t)(NROWB * blockIdx.x) * NPB;
    const float* xr1 = xr0 + NPB;

    for (int mode = 0; mode < 2; mode++) {
        float m0 = (mode == 1) ? mean_sh[0] : 0.0f;
        float m1 = (mode == 1) ? mean_sh[1] : 0.0f;
        if (tid >= 64)
            stage_tile2(xr0, xr1, buf[0], tid - 64, mode, m0, m1);
        __syncthreads();

        float p = 0.0f;
        for (int t = 0; t < NTILE; t++) {
            if (tid < NROWB * VF) {
                // 32 batches of 8 ds_read_b128, depth-3, immediate offsets
                unsigned base = lds_addr(&buf[t & 1][tid >> 3][tid & 7][0]);
                f32x4 A0, A1, A2, A3, A4, A5, A6, A7;
                f32x4 B0, B1, B2, B3, B4, B5, B6, B7;
                f32x4 C0, C1, C2, C3, C4, C5, C6, C7;
                ISSUE_A_O(0);
                ISSUE_B_O(128);
                TRIPLE(0) TRIPLE(1) TRIPLE(2) TRIPLE(3) TRIPLE(4)
                TRIPLE(5) TRIPLE(6) TRIPLE(7) TRIPLE(8) TRIPLE(9)
                WAIT8; ADD_A;              // batch 30
                WAIT0; ADD_B;              // batch 31
            } else if (tid >= 64 && t + 1 < NTILE) {
                stage_tile2(xr0 + (size_t)(t + 1) * TILE_R,
                            xr1 + (size_t)(t + 1) * TILE_R,
                            buf[(t + 1) & 1], tid - 64, mode, m0, m1);
            }
            __syncthreads();
        }
        if (tid < NROWB * VF) partial[tid >> 3][tid & 7] = p;
        __syncthreads();
        if (tid < NROWB) {
            float tr[VF];
            for (int j = 0; j < VF; j++) tr[j] = partial[tid][j];
            for (int w = VF / 2; w >= 1; w >>= 1)
                for (int j = 0; j < w; j++) tr[j] = __fadd_rn(tr[j], tr[j + w]);
            float S = tr[0];
            if (mode == 0) {
                mean_sh[tid] = __fdiv_rn(S, 262144.0f);
            } else {
                float var = __fdiv_rn(S, 262143.0f);
                float sd  = __fsqrt_rn(var);
                beta_out[NROWB * blockIdx.x + tid] = __fdiv_rn(sd, (float)(0.1 + 1e-6));
            }
        }
        __syncthreads();
    }
}

// ================= exact MSB radix-select (4 x 8-bit digits) =================
__device__ const unsigned pass_himask[4] = {0x00000000u, 0xFF000000u, 0xFFFF0000u, 0xFFFFFF00u};
__device__ const int      pass_shift[4]  = {24, 16, 8, 0};

// pass 0: vectorized key build (x4 + g4), acts cache write, zero-skip hist
__global__ void k_hist0(const float* __restrict__ x, const float* __restrict__ u,
                        const float* __restrict__ g, const float* __restrict__ beta,
                        float* __restrict__ acts_out, unsigned* __restrict__ cnt) {
    __shared__ unsigned lh[256];
    int row = blockIdx.x >> 4, blk = blockIdx.x & 15;
    lh[threadIdx.x] = 0;
    __syncthreads();
    float bt = beta[row];
    size_t base4 = ((size_t)row * NPB + (size_t)blk * (NPB / 16)) / 4;
    const float4* x4 = (const float4*)x;
    const float4* g4 = (const float4*)g;
    float4* a4 = (float4*)acts_out;
    unsigned zc = 0;
    for (int i = threadIdx.x; i < NPB / 16 / 4; i += 256) {
        float4 xx = x4[base4 + i];
        unsigned k[4];
        if (g) {
            float4 gg = g4[base4 + i];
            k[0] = key_from_g(xx.x, gg.x, bt); k[1] = key_from_g(xx.y, gg.y, bt);
            k[2] = key_from_g(xx.z, gg.z, bt); k[3] = key_from_g(xx.w, gg.w, bt);
        } else {
            const float4 uu = ((const float4*)u)[base4 + i];
            k[0] = act_key(xx.x, uu.x, bt); k[1] = act_key(xx.y, uu.y, bt);
            k[2] = act_key(xx.z, uu.z, bt); k[3] = act_key(xx.w, uu.w, bt);
        }
        if (acts_out) {
            float4 av;
            av.x = __uint_as_float(k[0]); av.y = __uint_as_float(k[1]);
            av.z = __uint_as_float(k[2]); av.w = __uint_as_float(k[3]);
            a4[base4 + i] = av;
        }
        #pragma unroll
        for (int q = 0; q < 4; q++) {
            if (k[q]) atomicAdd(&lh[k[q] >> 24], 1u);
            else      zc++;
        }
    }
    if (zc) atomicAdd(&lh[0], zc);
    __syncthreads();
    if (lh[threadIdx.x])
        atomicAdd(&cnt[(size_t)row * 256 + threadIdx.x], lh[threadIdx.x]);
}

// passes 1-3: vectorized acts read, conditional (rare) atomics
__global__ void k_histN(const float* __restrict__ x, const float* __restrict__ u,
                        const float* __restrict__ beta, const float* __restrict__ acts_in,
                        unsigned* __restrict__ cnt, const unsigned* __restrict__ prefix, int p) {
    __shared__ unsigned lh[256];
    int row = blockIdx.x >> 4, blk = blockIdx.x & 15;
    lh[threadIdx.x] = 0;
    __syncthreads();
    unsigned pfx = prefix[row];
    unsigned hm  = pass_himask[p];
    int sh = pass_shift[p];
    size_t base = (size_t)row * NPB + (size_t)blk * (NPB / 16);
    if (acts_in) {
        const float4* a4 = (const float4*)(acts_in + base);
        for (int i = threadIdx.x; i < NPB / 16 / 4; i += 256) {
            float4 av = a4[i];
            #pragma unroll
            for (int q = 0; q < 4; q++) {
                unsigned key = __float_as_uint((&av.x)[q]);
                if ((key & hm) == pfx)
                    atomicAdd(&lh[(key >> sh) & 255u], 1u);
            }
        }
    } else {
        float bt = beta[row];
        for (int i = threadIdx.x; i < NPB / 16; i += 256) {
            unsigned key = act_key(x[base + i], u[base + i], bt);
            if ((key & hm) == pfx)
                atomicAdd(&lh[(key >> sh) & 255u], 1u);
        }
    }
    __syncthreads();
    if (lh[threadIdx.x])
        atomicAdd(&cnt[(size_t)row * 256 + threadIdx.x], lh[threadIdx.x]);
}

// parallel k_sel: 256 threads, LDS suffix-scan; same integer semantics as the
// serial walk (select largest digit v with S[v] >= r; rank = r - S[v+1]).
__global__ void k_sel(const unsigned* __restrict__ cnt, unsigned* prefix, unsigned* rank, int p) {
    __shared__ unsigned sa[256], sb[256];
    int row = blockIdx.x;
    int t = threadIdx.x;
    unsigned h = cnt[(size_t)row * 256 + t];
    unsigned r   = (p == 0) ? K_SEL : rank[row];
    unsigned pfx = (p == 0) ? 0u : prefix[row];
    sa[t] = h;
    __syncthreads();
    unsigned* cur = sa; unsigned* nxt = sb;
    for (int off = 1; off < 256; off <<= 1) {
        unsigned v = cur[t] + ((t + off < 256) ? cur[t + off] : 0u);
        nxt[t] = v;
        __syncthreads();
        unsigned* tmp = cur; cur = nxt; nxt = tmp;
    }
    unsigned S_t  = cur[t];                        // sum_{v >= t} h[v]
    unsigned S_t1 = (t < 255) ? cur[t + 1] : 0u;   // sum_{v > t}
    if (S_t >= r && S_t1 < r) {
        prefix[row] = pfx | ((unsigned)t << pass_shift[p]);
        rank[row]   = r - S_t1;
    }
}

__global__ void k_write(const float* __restrict__ x, const float* __restrict__ u,
                        const float* __restrict__ beta, const float* __restrict__ acts_in,
                        const unsigned* __restrict__ prefix, float* __restrict__ out) {
    size_t e4 = (size_t)blockIdx.x * 256 + threadIdx.x;     // float4 index
    int row = (int)(e4 >> (LOG2_NPB - 2));
    unsigned kb = prefix[row];
    unsigned k[4];
    if (acts_in) {
        float4 av = ((const float4*)acts_in)[e4];
        #pragma unroll
        for (int q = 0; q < 4; q++) k[q] = __float_as_uint((&av.x)[q]);
    } else {
        float bt = beta[row];
        const float4 xx = ((const float4*)x)[e4];
        const float4 uu = ((const float4*)u)[e4];
        k[0] = act_key(xx.x, uu.x, bt); k[1] = act_key(xx.y, uu.y, bt);
        k[2] = act_key(xx.z, uu.z, bt); k[3] = act_key(xx.w, uu.w, bt);
    }
    float4 sp, mk;
    #pragma unroll
    for (int q = 0; q < 4; q++) {
        bool m = (k[q] >= kb);
        (&sp.x)[q] = m ? __uint_as_float(k[q]) : 0.0f;
        (&mk.x)[q] = m ? 1.0f : 0.0f;
    }
    ((float4*)out)[e4] = sp;
    ((float4*)(out + NTOT))[e4] = mk;
}

extern "C" void kernel_launch(void* const* d_in, const int* in_sizes, int n_in,
                              void* d_out, int out_size, void* d_ws, size_t ws_size,
                              hipStream_t stream) {
    const float* x = (const float*)d_in[0];
    const float* u = (const float*)d_in[1];
    float* out = (float*)d_out;
    char* ws = (char*)d_ws;

    float*    beta    = (float*)(ws + OFF_BETA);
    unsigned* cnt     = (unsigned*)(ws + OFF_CNT);
    unsigned* prefix  = (unsigned*)(ws + OFF_PFX);
    unsigned* rank    = (unsigned*)(ws + OFF_RANK);
    float*    acts    = (ws_size >= WS_NEED_ACTS) ? (float*)(ws + OFF_ACTS) : nullptr;
    float*    g       = (ws_size >= WS_NEED_G)    ? (float*)(ws + OFF_G)    : nullptr;

    hipMemsetAsync(ws + OFF_CNT, 0, 131328, stream);  // cnt + pfx + rank

    k_std<<<NBLK + GBLK, 256, 0, stream>>>(x, u, beta, g);

    k_hist0<<<NROWS * 16, 256, 0, stream>>>(x, u, g, beta, acts, cnt);
    k_sel  <<<NROWS, 256, 0, stream>>>(cnt, prefix, rank, 0);
    for (int p = 1; p < 4; p++) {
        k_histN<<<NROWS * 16, 256, 0, stream>>>(x, u, beta, acts,
                                                cnt + (size_t)p * NROWS * 256, prefix, p);
        k_sel  <<<NROWS, 256, 0, stream>>>(cnt + (size_t)p * NROWS * 256, prefix, rank, p);
    }

    k_write<<<NTOT / 4 / 256, 256, 0, stream>>>(x, u, beta, acts, prefix, out);
}